// Round 1
// baseline (412.073 us; speedup 1.0000x reference)
//
#include <hip/hip_runtime.h>

#define N_NODES 100000
#define N_EDGES 1600000
#define IN_DIM  256
#define OUT_DIM 64

// ---------------------------------------------------------------------------
// GEMM: h[i][j] = sum_k x[i][k] * w[k][j]   (fp32 vector ALU; no fp32 MFMA)
// lane j <-> output col j (OUT_DIM == wave size / 1 ... 64 cols, 64 lanes).
// W staged transposed+padded in LDS so each lane streams its column with
// ds_read_b128. Each wave computes 2 rows; block of 4 waves -> 8 rows.
// ---------------------------------------------------------------------------
#define GEMM_ROWS_PER_BLOCK 8

__global__ __launch_bounds__(256, 2)
void gcn_gemm_kernel(const float* __restrict__ x,
                     const float* __restrict__ w,
                     float* __restrict__ h)
{
    // transposed W: wt[j][k], padded stride 260 floats (1040 B, 16B-aligned)
    __shared__ float wt[OUT_DIM][IN_DIM + 4];

    // cooperative load + transpose: w[k*64 + j] -> wt[j][k]
    for (int idx = threadIdx.x; idx < IN_DIM * OUT_DIM; idx += 256) {
        int k = idx >> 6;     // /OUT_DIM
        int j = idx & 63;
        wt[j][k] = w[idx];    // coalesced global read
    }
    __syncthreads();

    const int lane = threadIdx.x & 63;
    const int wv   = threadIdx.x >> 6;
    const int r0   = blockIdx.x * GEMM_ROWS_PER_BLOCK + wv * 2;   // N_NODES % 8 == 0

    const float4* x0 = (const float4*)(x + (size_t)r0 * IN_DIM);
    const float4* x1 = (const float4*)(x + (size_t)(r0 + 1) * IN_DIM);
    const float4* wj = (const float4*)&wt[lane][0];

    float acc0 = 0.f, acc1 = 0.f;

#pragma unroll 8
    for (int kt = 0; kt < IN_DIM / 4; ++kt) {
        float4 wv4 = wj[kt];          // ds_read_b128, per-lane column slice
        float4 xa  = x0[kt];          // wave-uniform 16B global load (L1 bcast)
        float4 xb  = x1[kt];
        acc0 = fmaf(xa.x, wv4.x, acc0);
        acc0 = fmaf(xa.y, wv4.y, acc0);
        acc0 = fmaf(xa.z, wv4.z, acc0);
        acc0 = fmaf(xa.w, wv4.w, acc0);
        acc1 = fmaf(xb.x, wv4.x, acc1);
        acc1 = fmaf(xb.y, wv4.y, acc1);
        acc1 = fmaf(xb.z, wv4.z, acc1);
        acc1 = fmaf(xb.w, wv4.w, acc1);
    }

    h[(size_t)r0 * OUT_DIM + lane]       = acc0;
    h[(size_t)(r0 + 1) * OUT_DIM + lane] = acc1;
}

// ---------------------------------------------------------------------------
// SpMM + ReLU: out[r][j] = relu( sum_{e in row r} vals[e] * h[cols[e]][j] )
// adj_rows is sorted -> find row segment boundaries by binary search.
// One block = 256 threads handles 64 rows: 65 boundaries searched in
// parallel by 65 lanes (one latency chain per block), then 4 waves x 16
// rows each; lane j accumulates output dim j; each edge is one coalesced
// 256B read of h[col].
// ---------------------------------------------------------------------------
#define SPMM_ROWS_PER_BLOCK 64

__device__ __forceinline__ int lower_bound_rows(const int* __restrict__ rows, int val)
{
    int lo = 0, hi = N_EDGES;
    while (lo < hi) {
        int mid = (lo + hi) >> 1;
        if (rows[mid] < val) lo = mid + 1; else hi = mid;
    }
    return lo;
}

__global__ __launch_bounds__(256)
void gcn_spmm_relu_kernel(const float* __restrict__ h,
                          const float* __restrict__ vals,
                          const int* __restrict__ rows,
                          const int* __restrict__ cols,
                          float* __restrict__ out)
{
    __shared__ int starts[SPMM_ROWS_PER_BLOCK + 1];

    const int row0 = blockIdx.x * SPMM_ROWS_PER_BLOCK;
    const int t    = threadIdx.x;

    if (t <= SPMM_ROWS_PER_BLOCK) {
        int target = row0 + t;
        starts[t] = (target >= N_NODES) ? N_EDGES : lower_bound_rows(rows, target);
    }
    __syncthreads();

    const int lane = t & 63;
    const int wv   = t >> 6;

    for (int rr = wv * 16; rr < wv * 16 + 16; ++rr) {
        int r = row0 + rr;
        if (r >= N_NODES) break;
        int s = starts[rr];
        int e = starts[rr + 1];
        float acc = 0.f;
        for (int ei = s; ei < e; ++ei) {
            float v = vals[ei];                       // wave-uniform
            int   c = cols[ei];                       // wave-uniform
            acc = fmaf(v, h[(size_t)c * OUT_DIM + lane], acc);  // coalesced 256B
        }
        out[(size_t)r * OUT_DIM + lane] = fmaxf(acc, 0.f);
    }
}

// ---------------------------------------------------------------------------
extern "C" void kernel_launch(void* const* d_in, const int* in_sizes, int n_in,
                              void* d_out, int out_size, void* d_ws, size_t ws_size,
                              hipStream_t stream)
{
    const float* x    = (const float*)d_in[0];
    const float* w    = (const float*)d_in[1];
    const float* vals = (const float*)d_in[2];
    const int*   rows = (const int*)d_in[3];
    const int*   cols = (const int*)d_in[4];
    float*       out  = (float*)d_out;
    float*       h    = (float*)d_ws;   // N_NODES * OUT_DIM floats = 25.6 MB

    gcn_gemm_kernel<<<N_NODES / GEMM_ROWS_PER_BLOCK, 256, 0, stream>>>(x, w, h);

    gcn_spmm_relu_kernel<<<(N_NODES + SPMM_ROWS_PER_BLOCK - 1) / SPMM_ROWS_PER_BLOCK,
                           256, 0, stream>>>(h, vals, rows, cols, out);
}

// Round 2
// 310.659 us; speedup vs baseline: 1.3264x; 1.3264x over previous
//
#include <hip/hip_runtime.h>

#define N_NODES 100000
#define N_EDGES 1600000
#define IN_DIM  256
#define OUT_DIM 64

// ---------------------------------------------------------------------------
// GEMM: h[i][j] = sum_k x[i][k] * w[k][j]   (fp32 vector ALU; no fp32 MFMA)
// lane j <-> output col j. W staged transposed in LDS as float4 chunks:
// wt4[j][kt] (padded stride 65 float4 = 1040 B) -> lane j's ds_read_b128 at
// iter kt starts at bank 4*j mod 32; each 8-lane phase covers all 32 banks
// -> conflict-free. Block = 1024 threads (16 waves, 4/SIMD), 128 rows/block
// so the 64 KB W staging is amortized over 16x more compute than R1.
// Each wave: 8 rows, 8 independent FMA chains.
// ---------------------------------------------------------------------------
#define GEMM_BLOCK 1024
#define GEMM_ROWS_PER_WAVE 8
#define GEMM_ROWS_PER_BLOCK (16 * GEMM_ROWS_PER_WAVE)   // 128

__global__ __launch_bounds__(GEMM_BLOCK)
void gcn_gemm_kernel(const float* __restrict__ x,
                     const float* __restrict__ w,
                     float* __restrict__ h)
{
    __shared__ float4 wt4[OUT_DIM][IN_DIM / 4 + 1];   // [64][65], 66560 B

    // cooperative load + transpose: w[k*64 + j] -> wt4[j][k/4].component
    // 16 iterations per thread (amortized over 128 rows).
    for (int idx = threadIdx.x; idx < IN_DIM * OUT_DIM; idx += GEMM_BLOCK) {
        int k = idx >> 6;     // /OUT_DIM
        int j = idx & 63;
        ((float*)&wt4[j][0])[k] = w[idx];
    }
    __syncthreads();

    const int lane = threadIdx.x & 63;
    const int wv   = threadIdx.x >> 6;
    const int r0   = blockIdx.x * GEMM_ROWS_PER_BLOCK + wv * GEMM_ROWS_PER_WAVE;

    if (r0 >= N_NODES) return;

    const float4* wj = &wt4[lane][0];
    const float*  xb = x + (size_t)r0 * IN_DIM;

    if (r0 + GEMM_ROWS_PER_WAVE <= N_NODES) {
        // fast path: 8 full rows
        float acc[GEMM_ROWS_PER_WAVE];
#pragma unroll
        for (int r = 0; r < GEMM_ROWS_PER_WAVE; ++r) acc[r] = 0.f;

#pragma unroll 2
        for (int kt = 0; kt < IN_DIM / 4; ++kt) {
            float4 wv4 = wj[kt];                       // ds_read_b128, conflict-free
#pragma unroll
            for (int r = 0; r < GEMM_ROWS_PER_WAVE; ++r) {
                float4 xv = ((const float4*)(xb + (size_t)r * IN_DIM))[kt];
                float a = acc[r];
                a = fmaf(xv.x, wv4.x, a);
                a = fmaf(xv.y, wv4.y, a);
                a = fmaf(xv.z, wv4.z, a);
                a = fmaf(xv.w, wv4.w, a);
                acc[r] = a;
            }
        }
#pragma unroll
        for (int r = 0; r < GEMM_ROWS_PER_WAVE; ++r)
            h[(size_t)(r0 + r) * OUT_DIM + lane] = acc[r];
    } else {
        // tail path: per-row guarded
        for (int r = 0; r < GEMM_ROWS_PER_WAVE && r0 + r < N_NODES; ++r) {
            float acc = 0.f;
            const float4* xr = (const float4*)(xb + (size_t)r * IN_DIM);
#pragma unroll 4
            for (int kt = 0; kt < IN_DIM / 4; ++kt) {
                float4 wv4 = wj[kt];
                float4 xv  = xr[kt];
                acc = fmaf(xv.x, wv4.x, acc);
                acc = fmaf(xv.y, wv4.y, acc);
                acc = fmaf(xv.z, wv4.z, acc);
                acc = fmaf(xv.w, wv4.w, acc);
            }
            h[(size_t)(r0 + r) * OUT_DIM + lane] = acc;
        }
    }
}

// ---------------------------------------------------------------------------
// SpMM + ReLU: out[r][j] = relu( sum_{e in row r} vals[e] * h[cols[e]][j] )
// rows sorted -> block's 64-row edge segment is CONTIGUOUS: stage its
// (vals, cols) into LDS cooperatively (coalesced), inner loop reads them as
// conflict-free broadcast LDS reads; h-gather (256 B coalesced per edge)
// 2-way unrolled with 2 accumulators for memory-level parallelism.
// ---------------------------------------------------------------------------
#define SPMM_ROWS_PER_BLOCK 64
#define SEG_CAP 2048   // mean edges/block = 1024, sd ~32; fallback if exceeded

__device__ __forceinline__ int lower_bound_rows(const int* __restrict__ rows, int val)
{
    int lo = 0, hi = N_EDGES;
    while (lo < hi) {
        int mid = (lo + hi) >> 1;
        if (rows[mid] < val) lo = mid + 1; else hi = mid;
    }
    return lo;
}

__global__ __launch_bounds__(256)
void gcn_spmm_relu_kernel(const float* __restrict__ h,
                          const float* __restrict__ vals,
                          const int* __restrict__ rows,
                          const int* __restrict__ cols,
                          float* __restrict__ out)
{
    __shared__ int   starts[SPMM_ROWS_PER_BLOCK + 1];
    __shared__ float s_vals[SEG_CAP];
    __shared__ int   s_cols[SEG_CAP];

    const int row0 = blockIdx.x * SPMM_ROWS_PER_BLOCK;
    const int t    = threadIdx.x;

    if (t <= SPMM_ROWS_PER_BLOCK) {
        int target = row0 + t;
        starts[t] = (target >= N_NODES) ? N_EDGES : lower_bound_rows(rows, target);
    }
    __syncthreads();

    const int seg0   = starts[0];
    const int segEnd = starts[SPMM_ROWS_PER_BLOCK];
    const int segLen = segEnd - seg0;
    const bool fits  = (segLen <= SEG_CAP);

    if (fits) {
        for (int i = t; i < segLen; i += 256) {
            s_vals[i] = vals[seg0 + i];    // coalesced
            s_cols[i] = cols[seg0 + i];
        }
    }
    __syncthreads();

    const int lane = t & 63;
    const int wv   = t >> 6;

    for (int rr = wv; rr < SPMM_ROWS_PER_BLOCK; rr += 4) {
        int r = row0 + rr;
        if (r >= N_NODES) break;
        int s = starts[rr]     - seg0;
        int e = starts[rr + 1] - seg0;
        float acc0 = 0.f, acc1 = 0.f;
        if (fits) {
            int ei = s;
            for (; ei + 1 < e; ei += 2) {
                float v0 = s_vals[ei];     int c0 = s_cols[ei];       // LDS broadcast
                float v1 = s_vals[ei + 1]; int c1 = s_cols[ei + 1];
                acc0 = fmaf(v0, h[(size_t)c0 * OUT_DIM + lane], acc0);  // coalesced 256B
                acc1 = fmaf(v1, h[(size_t)c1 * OUT_DIM + lane], acc1);
            }
            if (ei < e) {
                acc0 = fmaf(s_vals[ei], h[(size_t)s_cols[ei] * OUT_DIM + lane], acc0);
            }
        } else {
            // overflow fallback: straight global reads (essentially never taken)
            for (int ei = s; ei < e; ++ei) {
                float v = vals[seg0 + ei];
                int   c = cols[seg0 + ei];
                acc0 = fmaf(v, h[(size_t)c * OUT_DIM + lane], acc0);
            }
        }
        out[(size_t)r * OUT_DIM + lane] = fmaxf(acc0 + acc1, 0.f);
    }
}

// ---------------------------------------------------------------------------
extern "C" void kernel_launch(void* const* d_in, const int* in_sizes, int n_in,
                              void* d_out, int out_size, void* d_ws, size_t ws_size,
                              hipStream_t stream)
{
    const float* x    = (const float*)d_in[0];
    const float* w    = (const float*)d_in[1];
    const float* vals = (const float*)d_in[2];
    const int*   rows = (const int*)d_in[3];
    const int*   cols = (const int*)d_in[4];
    float*       out  = (float*)d_out;
    float*       h    = (float*)d_ws;   // N_NODES * OUT_DIM floats = 25.6 MB

    const int gemm_grid = (N_NODES + GEMM_ROWS_PER_BLOCK - 1) / GEMM_ROWS_PER_BLOCK;
    gcn_gemm_kernel<<<gemm_grid, GEMM_BLOCK, 0, stream>>>(x, w, h);

    const int spmm_grid = (N_NODES + SPMM_ROWS_PER_BLOCK - 1) / SPMM_ROWS_PER_BLOCK;
    gcn_spmm_relu_kernel<<<spmm_grid, 256, 0, stream>>>(h, vals, rows, cols, out);
}

// Round 3
// 104.066 us; speedup vs baseline: 3.9597x; 2.9852x over previous
//
#include <hip/hip_runtime.h>

#define N_NODES 100000
#define N_EDGES 1600000
#define IN_DIM  256
#define OUT_DIM 64

typedef __attribute__((ext_vector_type(8))) short bf16x8;   // 8 bf16 in 4 VGPRs
typedef __attribute__((ext_vector_type(4))) float f32x4;    // MFMA accumulator

// float -> bf16 (round-to-nearest-even)
__device__ __forceinline__ short f2bf(float f) {
    union { float f; unsigned u; } v; v.f = f;
    unsigned r = v.u + 0x7fffu + ((v.u >> 16) & 1u);
    return (short)(r >> 16);
}

// ---------------------------------------------------------------------------
// GEMM via bf16 MFMA: h[i][j] = sum_k x[i][k] * w[k][j]
// Block = 256 threads (4 waves), 64 rows/block; wave w owns rows [r0, r0+16),
// all 64 cols via 4 accumulators (n0 = 0,16,32,48). K-loop: 8 steps of 32.
// A-frag: per-lane row = lane&15, k = (lane>>4)*8 + i  -> two coalesced-ish
//   16B global loads per step per lane, converted fp32->bf16 in-register.
//   Every x byte is read exactly once; kernel is HBM-bound.
// B-frag: W staged once per block into LDS as bf16, layout wb[n][k] with
//   padded stride 264 (528 B; bank advance 4/row -> <=2-way conflict, free).
// C/D: col = lane&15, row = (lane>>4)*4 + reg (verified triple from guide).
// ---------------------------------------------------------------------------
#define WB_STRIDE 264   // bf16 elems per n-row: 256 + 8 pad; 528 B, 16B-aligned

__global__ __launch_bounds__(256)
void gcn_gemm_mfma(const float* __restrict__ x,
                   const float* __restrict__ w,
                   float* __restrict__ h)
{
    __shared__ short wb[OUT_DIM * WB_STRIDE];   // 33792 B

    // stage W -> LDS bf16, transposed to wb[n][k] (global read coalesced)
    for (int idx = threadIdx.x; idx < IN_DIM * OUT_DIM; idx += 256) {
        int k = idx >> 6;     // idx / OUT_DIM
        int n = idx & 63;
        wb[n * WB_STRIDE + k] = f2bf(w[idx]);
    }
    __syncthreads();

    const int lane = threadIdx.x & 63;
    const int wv   = threadIdx.x >> 6;
    const int r0   = blockIdx.x * 64 + wv * 16;

    // A-fragment source pointer (row clamped for tail block; stores are guarded)
    const int arow   = r0 + (lane & 15);
    const int arow_c = arow < N_NODES ? arow : N_NODES - 1;
    const int kbase  = (lane >> 4) << 3;                    // 0,8,16,24
    const float* xr  = x + (size_t)arow_c * IN_DIM + kbase;

    const int nlo = lane & 15;
    const short* wb0 = &wb[(0  + nlo) * WB_STRIDE + kbase];
    const short* wb1 = &wb[(16 + nlo) * WB_STRIDE + kbase];
    const short* wb2 = &wb[(32 + nlo) * WB_STRIDE + kbase];
    const short* wb3 = &wb[(48 + nlo) * WB_STRIDE + kbase];

    f32x4 acc0 = {0.f, 0.f, 0.f, 0.f};
    f32x4 acc1 = {0.f, 0.f, 0.f, 0.f};
    f32x4 acc2 = {0.f, 0.f, 0.f, 0.f};
    f32x4 acc3 = {0.f, 0.f, 0.f, 0.f};

#pragma unroll
    for (int k0 = 0; k0 < IN_DIM; k0 += 32) {
        float4 f0 = *(const float4*)(xr + k0);      // 16B global
        float4 f1 = *(const float4*)(xr + k0 + 4);  // 16B global
        bf16x8 a;
        a[0] = f2bf(f0.x); a[1] = f2bf(f0.y); a[2] = f2bf(f0.z); a[3] = f2bf(f0.w);
        a[4] = f2bf(f1.x); a[5] = f2bf(f1.y); a[6] = f2bf(f1.z); a[7] = f2bf(f1.w);

        bf16x8 b0 = *(const bf16x8*)(wb0 + k0);     // ds_read_b128
        bf16x8 b1 = *(const bf16x8*)(wb1 + k0);
        bf16x8 b2 = *(const bf16x8*)(wb2 + k0);
        bf16x8 b3 = *(const bf16x8*)(wb3 + k0);

        acc0 = __builtin_amdgcn_mfma_f32_16x16x32_bf16(a, b0, acc0, 0, 0, 0);
        acc1 = __builtin_amdgcn_mfma_f32_16x16x32_bf16(a, b1, acc1, 0, 0, 0);
        acc2 = __builtin_amdgcn_mfma_f32_16x16x32_bf16(a, b2, acc2, 0, 0, 0);
        acc3 = __builtin_amdgcn_mfma_f32_16x16x32_bf16(a, b3, acc3, 0, 0, 0);
    }

    // C write: row = r0 + (lane>>4)*4 + rr, col = n0 + (lane&15)
    const int crow0 = r0 + ((lane >> 4) << 2);
#pragma unroll
    for (int rr = 0; rr < 4; ++rr) {
        int row = crow0 + rr;
        if (row < N_NODES) {
            float* hp = h + (size_t)row * OUT_DIM + nlo;
            hp[0]  = acc0[rr];
            hp[16] = acc1[rr];
            hp[32] = acc2[rr];
            hp[48] = acc3[rr];
        }
    }
}

// ---------------------------------------------------------------------------
// SpMM + ReLU (unchanged from R2: ~26 us): rows sorted -> contiguous block
// segment staged in LDS; lane j accumulates dim j; coalesced 256B h-gather.
// ---------------------------------------------------------------------------
#define SPMM_ROWS_PER_BLOCK 64
#define SEG_CAP 2048

__device__ __forceinline__ int lower_bound_rows(const int* __restrict__ rows, int val)
{
    int lo = 0, hi = N_EDGES;
    while (lo < hi) {
        int mid = (lo + hi) >> 1;
        if (rows[mid] < val) lo = mid + 1; else hi = mid;
    }
    return lo;
}

__global__ __launch_bounds__(256)
void gcn_spmm_relu_kernel(const float* __restrict__ h,
                          const float* __restrict__ vals,
                          const int* __restrict__ rows,
                          const int* __restrict__ cols,
                          float* __restrict__ out)
{
    __shared__ int   starts[SPMM_ROWS_PER_BLOCK + 1];
    __shared__ float s_vals[SEG_CAP];
    __shared__ int   s_cols[SEG_CAP];

    const int row0 = blockIdx.x * SPMM_ROWS_PER_BLOCK;
    const int t    = threadIdx.x;

    if (t <= SPMM_ROWS_PER_BLOCK) {
        int target = row0 + t;
        starts[t] = (target >= N_NODES) ? N_EDGES : lower_bound_rows(rows, target);
    }
    __syncthreads();

    const int seg0   = starts[0];
    const int segEnd = starts[SPMM_ROWS_PER_BLOCK];
    const int segLen = segEnd - seg0;
    const bool fits  = (segLen <= SEG_CAP);

    if (fits) {
        for (int i = t; i < segLen; i += 256) {
            s_vals[i] = vals[seg0 + i];
            s_cols[i] = cols[seg0 + i];
        }
    }
    __syncthreads();

    const int lane = t & 63;
    const int wv   = t >> 6;

    for (int rr = wv; rr < SPMM_ROWS_PER_BLOCK; rr += 4) {
        int r = row0 + rr;
        if (r >= N_NODES) break;
        int s = starts[rr]     - seg0;
        int e = starts[rr + 1] - seg0;
        float acc0 = 0.f, acc1 = 0.f;
        if (fits) {
            int ei = s;
            for (; ei + 1 < e; ei += 2) {
                float v0 = s_vals[ei];     int c0 = s_cols[ei];
                float v1 = s_vals[ei + 1]; int c1 = s_cols[ei + 1];
                acc0 = fmaf(v0, h[(size_t)c0 * OUT_DIM + lane], acc0);
                acc1 = fmaf(v1, h[(size_t)c1 * OUT_DIM + lane], acc1);
            }
            if (ei < e) {
                acc0 = fmaf(s_vals[ei], h[(size_t)s_cols[ei] * OUT_DIM + lane], acc0);
            }
        } else {
            for (int ei = s; ei < e; ++ei) {
                float v = vals[seg0 + ei];
                int   c = cols[seg0 + ei];
                acc0 = fmaf(v, h[(size_t)c * OUT_DIM + lane], acc0);
            }
        }
        out[(size_t)r * OUT_DIM + lane] = fmaxf(acc0 + acc1, 0.f);
    }
}

// ---------------------------------------------------------------------------
extern "C" void kernel_launch(void* const* d_in, const int* in_sizes, int n_in,
                              void* d_out, int out_size, void* d_ws, size_t ws_size,
                              hipStream_t stream)
{
    const float* x    = (const float*)d_in[0];
    const float* w    = (const float*)d_in[1];
    const float* vals = (const float*)d_in[2];
    const int*   rows = (const int*)d_in[3];
    const int*   cols = (const int*)d_in[4];
    float*       out  = (float*)d_out;
    float*       h    = (float*)d_ws;   // N_NODES * OUT_DIM floats = 25.6 MB

    const int gemm_grid = (N_NODES + 63) / 64;
    gcn_gemm_mfma<<<gemm_grid, 256, 0, stream>>>(x, w, h);

    const int spmm_grid = (N_NODES + SPMM_ROWS_PER_BLOCK - 1) / SPMM_ROWS_PER_BLOCK;
    gcn_spmm_relu_kernel<<<spmm_grid, 256, 0, stream>>>(h, vals, rows, cols, out);
}

// Round 4
// 79.916 us; speedup vs baseline: 5.1563x; 1.3022x over previous
//
#include <hip/hip_runtime.h>

#define N_NODES 100000
#define N_EDGES 1600000
#define IN_DIM  256
#define OUT_DIM 64

typedef __attribute__((ext_vector_type(8))) short bf16x8;   // 8 bf16 in 4 VGPRs
typedef __attribute__((ext_vector_type(4))) float f32x4;    // MFMA accumulator

// float -> bf16 (round-to-nearest-even)
__device__ __forceinline__ short f2bf(float f) {
    union { float f; unsigned u; } v; v.f = f;
    unsigned r = v.u + 0x7fffu + ((v.u >> 16) & 1u);
    return (short)(r >> 16);
}
// bf16 (as ushort) -> float
__device__ __forceinline__ float bf2f(unsigned short us) {
    union { unsigned u; float f; } v; v.u = ((unsigned)us) << 16;
    return v.f;
}

// ---------------------------------------------------------------------------
// GEMM via bf16 MFMA: h[i][j] = sum_k x[i][k] * w[k][j]; h stored as BF16
// (halves GEMM write traffic and, more importantly, SpMM gather traffic).
// Block = 256 threads (4 waves), 64 rows/block; wave owns 16 rows x 64 cols.
// A-frag per-lane fp32 loads converted in-register; B staged in LDS bf16.
// ---------------------------------------------------------------------------
#define WB_STRIDE 264   // bf16 elems per n-row: 256 + 8 pad

__global__ __launch_bounds__(256)
void gcn_gemm_mfma(const float* __restrict__ x,
                   const float* __restrict__ w,
                   unsigned short* __restrict__ hb)
{
    __shared__ short wb[OUT_DIM * WB_STRIDE];   // 33792 B

    for (int idx = threadIdx.x; idx < IN_DIM * OUT_DIM; idx += 256) {
        int k = idx >> 6;
        int n = idx & 63;
        wb[n * WB_STRIDE + k] = f2bf(w[idx]);
    }
    __syncthreads();

    const int lane = threadIdx.x & 63;
    const int wv   = threadIdx.x >> 6;
    const int r0   = blockIdx.x * 64 + wv * 16;

    const int arow   = r0 + (lane & 15);
    const int arow_c = arow < N_NODES ? arow : N_NODES - 1;
    const int kbase  = (lane >> 4) << 3;                    // 0,8,16,24
    const float* xr  = x + (size_t)arow_c * IN_DIM + kbase;

    const int nlo = lane & 15;
    const short* wb0 = &wb[(0  + nlo) * WB_STRIDE + kbase];
    const short* wb1 = &wb[(16 + nlo) * WB_STRIDE + kbase];
    const short* wb2 = &wb[(32 + nlo) * WB_STRIDE + kbase];
    const short* wb3 = &wb[(48 + nlo) * WB_STRIDE + kbase];

    f32x4 acc0 = {0.f, 0.f, 0.f, 0.f};
    f32x4 acc1 = {0.f, 0.f, 0.f, 0.f};
    f32x4 acc2 = {0.f, 0.f, 0.f, 0.f};
    f32x4 acc3 = {0.f, 0.f, 0.f, 0.f};

#pragma unroll
    for (int k0 = 0; k0 < IN_DIM; k0 += 32) {
        float4 f0 = *(const float4*)(xr + k0);
        float4 f1 = *(const float4*)(xr + k0 + 4);
        bf16x8 a;
        a[0] = f2bf(f0.x); a[1] = f2bf(f0.y); a[2] = f2bf(f0.z); a[3] = f2bf(f0.w);
        a[4] = f2bf(f1.x); a[5] = f2bf(f1.y); a[6] = f2bf(f1.z); a[7] = f2bf(f1.w);

        bf16x8 b0 = *(const bf16x8*)(wb0 + k0);
        bf16x8 b1 = *(const bf16x8*)(wb1 + k0);
        bf16x8 b2 = *(const bf16x8*)(wb2 + k0);
        bf16x8 b3 = *(const bf16x8*)(wb3 + k0);

        acc0 = __builtin_amdgcn_mfma_f32_16x16x32_bf16(a, b0, acc0, 0, 0, 0);
        acc1 = __builtin_amdgcn_mfma_f32_16x16x32_bf16(a, b1, acc1, 0, 0, 0);
        acc2 = __builtin_amdgcn_mfma_f32_16x16x32_bf16(a, b2, acc2, 0, 0, 0);
        acc3 = __builtin_amdgcn_mfma_f32_16x16x32_bf16(a, b3, acc3, 0, 0, 0);
    }

    const int crow0 = r0 + ((lane >> 4) << 2);
#pragma unroll
    for (int rr = 0; rr < 4; ++rr) {
        int row = crow0 + rr;
        if (row < N_NODES) {
            unsigned short* hp = hb + (size_t)row * OUT_DIM + nlo;
            hp[0]  = (unsigned short)f2bf(acc0[rr]);
            hp[16] = (unsigned short)f2bf(acc1[rr]);
            hp[32] = (unsigned short)f2bf(acc2[rr]);
            hp[48] = (unsigned short)f2bf(acc3[rr]);
        }
    }
}

// ---------------------------------------------------------------------------
// SpMM + ReLU over bf16 h: out[r][j] = relu( sum_e vals[e] * h[cols[e]][j] )
// rows sorted -> block's 64-row edge segment contiguous; (vals,cols) staged
// in LDS. Gather: 128 B/wave coalesced bf16 row reads, 4 independent
// accumulator chains for memory-level parallelism.
// ---------------------------------------------------------------------------
#define SPMM_ROWS_PER_BLOCK 64
#define SEG_CAP 2048

__device__ __forceinline__ int lower_bound_rows(const int* __restrict__ rows, int val)
{
    int lo = 0, hi = N_EDGES;
    while (lo < hi) {
        int mid = (lo + hi) >> 1;
        if (rows[mid] < val) lo = mid + 1; else hi = mid;
    }
    return lo;
}

__global__ __launch_bounds__(256)
void gcn_spmm_relu_kernel(const unsigned short* __restrict__ hb,
                          const float* __restrict__ vals,
                          const int* __restrict__ rows,
                          const int* __restrict__ cols,
                          float* __restrict__ out)
{
    __shared__ int   starts[SPMM_ROWS_PER_BLOCK + 1];
    __shared__ float s_vals[SEG_CAP];
    __shared__ int   s_cols[SEG_CAP];

    const int row0 = blockIdx.x * SPMM_ROWS_PER_BLOCK;
    const int t    = threadIdx.x;

    if (t <= SPMM_ROWS_PER_BLOCK) {
        int target = row0 + t;
        starts[t] = (target >= N_NODES) ? N_EDGES : lower_bound_rows(rows, target);
    }
    __syncthreads();

    const int seg0   = starts[0];
    const int segEnd = starts[SPMM_ROWS_PER_BLOCK];
    const int segLen = segEnd - seg0;
    const bool fits  = (segLen <= SEG_CAP);

    if (fits) {
        for (int i = t; i < segLen; i += 256) {
            s_vals[i] = vals[seg0 + i];
            s_cols[i] = cols[seg0 + i];
        }
    }
    __syncthreads();

    const int lane = t & 63;
    const int wv   = t >> 6;

    for (int rr = wv; rr < SPMM_ROWS_PER_BLOCK; rr += 4) {
        int r = row0 + rr;
        if (r >= N_NODES) break;
        int s = starts[rr]     - seg0;
        int e = starts[rr + 1] - seg0;
        float acc0 = 0.f, acc1 = 0.f, acc2 = 0.f, acc3 = 0.f;
        if (fits) {
            int ei = s;
            for (; ei + 3 < e; ei += 4) {
                float v0 = s_vals[ei];     int c0 = s_cols[ei];
                float v1 = s_vals[ei + 1]; int c1 = s_cols[ei + 1];
                float v2 = s_vals[ei + 2]; int c2 = s_cols[ei + 2];
                float v3 = s_vals[ei + 3]; int c3 = s_cols[ei + 3];
                float h0 = bf2f(hb[(size_t)c0 * OUT_DIM + lane]);   // 128B/wave
                float h1 = bf2f(hb[(size_t)c1 * OUT_DIM + lane]);
                float h2 = bf2f(hb[(size_t)c2 * OUT_DIM + lane]);
                float h3 = bf2f(hb[(size_t)c3 * OUT_DIM + lane]);
                acc0 = fmaf(v0, h0, acc0);
                acc1 = fmaf(v1, h1, acc1);
                acc2 = fmaf(v2, h2, acc2);
                acc3 = fmaf(v3, h3, acc3);
            }
            for (; ei < e; ++ei) {
                acc0 = fmaf(s_vals[ei], bf2f(hb[(size_t)s_cols[ei] * OUT_DIM + lane]), acc0);
            }
        } else {
            for (int ei = s; ei < e; ++ei) {
                float v = vals[seg0 + ei];
                int   c = cols[seg0 + ei];
                acc0 = fmaf(v, bf2f(hb[(size_t)c * OUT_DIM + lane]), acc0);
            }
        }
        out[(size_t)r * OUT_DIM + lane] = fmaxf((acc0 + acc1) + (acc2 + acc3), 0.f);
    }
}

// ---------------------------------------------------------------------------
extern "C" void kernel_launch(void* const* d_in, const int* in_sizes, int n_in,
                              void* d_out, int out_size, void* d_ws, size_t ws_size,
                              hipStream_t stream)
{
    const float* x    = (const float*)d_in[0];
    const float* w    = (const float*)d_in[1];
    const float* vals = (const float*)d_in[2];
    const int*   rows = (const int*)d_in[3];
    const int*   cols = (const int*)d_in[4];
    float*       out  = (float*)d_out;
    unsigned short* hb = (unsigned short*)d_ws;   // N_NODES*OUT_DIM bf16 = 12.8 MB

    const int gemm_grid = (N_NODES + 63) / 64;
    gcn_gemm_mfma<<<gemm_grid, 256, 0, stream>>>(x, w, hb);

    const int spmm_grid = (N_NODES + SPMM_ROWS_PER_BLOCK - 1) / SPMM_ROWS_PER_BLOCK;
    gcn_spmm_relu_kernel<<<spmm_grid, 256, 0, stream>>>(hb, vals, rows, cols, out);
}

// Round 5
// 78.471 us; speedup vs baseline: 5.2513x; 1.0184x over previous
//
#include <hip/hip_runtime.h>

#define N_NODES 100000
#define N_EDGES 1600000
#define IN_DIM  256
#define OUT_DIM 64

typedef __attribute__((ext_vector_type(8))) short bf16x8;   // 8 bf16 in 4 VGPRs
typedef __attribute__((ext_vector_type(4))) float f32x4;    // MFMA accumulator

// float -> bf16 (round-to-nearest-even)
__device__ __forceinline__ short f2bf(float f) {
    union { float f; unsigned u; } v; v.f = f;
    unsigned r = v.u + 0x7fffu + ((v.u >> 16) & 1u);
    return (short)(r >> 16);
}

// ---------------------------------------------------------------------------
// GEMM via bf16 MFMA: h = x @ w, stored bf16. (~19 us, near its 16 us HBM
// floor: x read 102.4 MB.) Unchanged from R4.
// ---------------------------------------------------------------------------
#define WB_STRIDE 264   // bf16 elems per n-row: 256 + 8 pad

__global__ __launch_bounds__(256)
void gcn_gemm_mfma(const float* __restrict__ x,
                   const float* __restrict__ w,
                   unsigned short* __restrict__ hb)
{
    __shared__ short wb[OUT_DIM * WB_STRIDE];   // 33792 B

    for (int idx = threadIdx.x; idx < IN_DIM * OUT_DIM; idx += 256) {
        int k = idx >> 6;
        int n = idx & 63;
        wb[n * WB_STRIDE + k] = f2bf(w[idx]);
    }
    __syncthreads();

    const int lane = threadIdx.x & 63;
    const int wv   = threadIdx.x >> 6;
    const int r0   = blockIdx.x * 64 + wv * 16;

    const int arow   = r0 + (lane & 15);
    const int arow_c = arow < N_NODES ? arow : N_NODES - 1;
    const int kbase  = (lane >> 4) << 3;                    // 0,8,16,24
    const float* xr  = x + (size_t)arow_c * IN_DIM + kbase;

    const int nlo = lane & 15;
    const short* wb0 = &wb[(0  + nlo) * WB_STRIDE + kbase];
    const short* wb1 = &wb[(16 + nlo) * WB_STRIDE + kbase];
    const short* wb2 = &wb[(32 + nlo) * WB_STRIDE + kbase];
    const short* wb3 = &wb[(48 + nlo) * WB_STRIDE + kbase];

    f32x4 acc0 = {0.f, 0.f, 0.f, 0.f};
    f32x4 acc1 = {0.f, 0.f, 0.f, 0.f};
    f32x4 acc2 = {0.f, 0.f, 0.f, 0.f};
    f32x4 acc3 = {0.f, 0.f, 0.f, 0.f};

#pragma unroll
    for (int k0 = 0; k0 < IN_DIM; k0 += 32) {
        float4 f0 = *(const float4*)(xr + k0);
        float4 f1 = *(const float4*)(xr + k0 + 4);
        bf16x8 a;
        a[0] = f2bf(f0.x); a[1] = f2bf(f0.y); a[2] = f2bf(f0.z); a[3] = f2bf(f0.w);
        a[4] = f2bf(f1.x); a[5] = f2bf(f1.y); a[6] = f2bf(f1.z); a[7] = f2bf(f1.w);

        bf16x8 b0 = *(const bf16x8*)(wb0 + k0);
        bf16x8 b1 = *(const bf16x8*)(wb1 + k0);
        bf16x8 b2 = *(const bf16x8*)(wb2 + k0);
        bf16x8 b3 = *(const bf16x8*)(wb3 + k0);

        acc0 = __builtin_amdgcn_mfma_f32_16x16x32_bf16(a, b0, acc0, 0, 0, 0);
        acc1 = __builtin_amdgcn_mfma_f32_16x16x32_bf16(a, b1, acc1, 0, 0, 0);
        acc2 = __builtin_amdgcn_mfma_f32_16x16x32_bf16(a, b2, acc2, 0, 0, 0);
        acc3 = __builtin_amdgcn_mfma_f32_16x16x32_bf16(a, b3, acc3, 0, 0, 0);
    }

    const int crow0 = r0 + ((lane >> 4) << 2);
#pragma unroll
    for (int rr = 0; rr < 4; ++rr) {
        int row = crow0 + rr;
        if (row < N_NODES) {
            unsigned short* hp = hb + (size_t)row * OUT_DIM + nlo;
            hp[0]  = (unsigned short)f2bf(acc0[rr]);
            hp[16] = (unsigned short)f2bf(acc1[rr]);
            hp[32] = (unsigned short)f2bf(acc2[rr]);
            hp[48] = (unsigned short)f2bf(acc3[rr]);
        }
    }
}

// ---------------------------------------------------------------------------
// SpMM + ReLU, half-wave-paired gather:
//   lanes 0-31 process even edges of a row, lanes 32-63 odd edges; each lane
//   reads one uint = 2 bf16 dims -> one global_load_dword covers TWO edge
//   rows (256 B). 4 unrolled chains = 8 edges in flight per wave. Row ends
//   with one __shfl_xor(.,32) combine; lanes 0-31 store float2.
// 32 rows/block (3125 blocks) for occupancy/balance; (val,col) pairs staged
// interleaved in LDS (one ds_read_b64 per edge-pair per lane).
// ---------------------------------------------------------------------------
#define SPMM_ROWS_PER_BLOCK 32
#define SEG_CAP 1024   // mean edges/block = 512, sd ~23; fallback if exceeded

__device__ __forceinline__ int lower_bound_rows(const int* __restrict__ rows, int val)
{
    int lo = 0, hi = N_EDGES;
    while (lo < hi) {
        int mid = (lo + hi) >> 1;
        if (rows[mid] < val) lo = mid + 1; else hi = mid;
    }
    return lo;
}

__global__ __launch_bounds__(256)
void gcn_spmm_relu_kernel(const unsigned short* __restrict__ hb,
                          const float* __restrict__ vals,
                          const int* __restrict__ rows,
                          const int* __restrict__ cols,
                          float* __restrict__ out)
{
    __shared__ int   starts[SPMM_ROWS_PER_BLOCK + 1];
    __shared__ uint2 s_ec[SEG_CAP];   // .x = val bits, .y = col

    const int row0 = blockIdx.x * SPMM_ROWS_PER_BLOCK;
    const int t    = threadIdx.x;

    if (t <= SPMM_ROWS_PER_BLOCK) {
        int target = row0 + t;
        starts[t] = (target >= N_NODES) ? N_EDGES : lower_bound_rows(rows, target);
    }
    __syncthreads();

    const int seg0   = starts[0];
    const int segLen = starts[SPMM_ROWS_PER_BLOCK] - seg0;
    const bool fits  = (segLen <= SEG_CAP);

    if (fits) {
        for (int i = t; i < segLen; i += 256) {
            s_ec[i] = make_uint2(__float_as_uint(vals[seg0 + i]),
                                 (unsigned)cols[seg0 + i]);
        }
    }
    __syncthreads();

    const int lane = t & 63;
    const int wv   = t >> 6;
    const int half = lane >> 5;       // 0: even edges, 1: odd edges
    const int sub  = lane & 31;       // dim pair index: dims 2*sub, 2*sub+1

    for (int rr = wv; rr < SPMM_ROWS_PER_BLOCK; rr += 4) {
        const int r = row0 + rr;
        const int s = starts[rr]     - seg0;
        const int e = starts[rr + 1] - seg0;
        const int n  = e - s;
        const int tc = (n + 1) >> 1;              // paired iterations

        float aL0 = 0.f, aH0 = 0.f, aL1 = 0.f, aH1 = 0.f;
        float aL2 = 0.f, aH2 = 0.f, aL3 = 0.f, aH3 = 0.f;

        if (fits) {
#define STEP_L(i_, aL_, aH_)                                                   \
            {                                                                  \
                int ei    = s + 2 * (i_) + half;                               \
                bool ok   = ei < e;                                            \
                int eidx  = ok ? ei : e - 1;                                   \
                uint2 vc  = s_ec[eidx];                                        \
                float v   = ok ? __uint_as_float(vc.x) : 0.f;                  \
                unsigned hx = *(const unsigned*)(hb + (size_t)vc.y * OUT_DIM   \
                                                 + 2u * sub);                  \
                aL_ = fmaf(v, __uint_as_float(hx << 16), aL_);                 \
                aH_ = fmaf(v, __uint_as_float(hx & 0xffff0000u), aH_);         \
            }
            int i = 0;
            for (; i + 3 < tc; i += 4) {
                STEP_L(i + 0, aL0, aH0)
                STEP_L(i + 1, aL1, aH1)
                STEP_L(i + 2, aL2, aH2)
                STEP_L(i + 3, aL3, aH3)
            }
            for (; i < tc; ++i) {
                STEP_L(i, aL0, aH0)
            }
#undef STEP_L
        } else {
            // overflow fallback (essentially never): same pairing, global reads
            for (int i = 0; i < tc; ++i) {
                int ei   = s + 2 * i + half;
                bool ok  = ei < e;
                int eidx = (ok ? ei : e - 1) + seg0;
                float v  = ok ? vals[eidx] : 0.f;
                unsigned c = (unsigned)cols[eidx];
                unsigned hx = *(const unsigned*)(hb + (size_t)c * OUT_DIM + 2u * sub);
                aL0 = fmaf(v, __uint_as_float(hx << 16), aL0);
                aH0 = fmaf(v, __uint_as_float(hx & 0xffff0000u), aH0);
            }
        }

        float lo = (aL0 + aL1) + (aL2 + aL3);
        float hi = (aH0 + aH1) + (aH2 + aH3);
        lo += __shfl_xor(lo, 32);
        hi += __shfl_xor(hi, 32);

        if (half == 0) {
            float2 o;
            o.x = fmaxf(lo, 0.f);
            o.y = fmaxf(hi, 0.f);
            *(float2*)(out + (size_t)r * OUT_DIM + 2u * sub) = o;   // 256B/half-wave
        }
    }
}

// ---------------------------------------------------------------------------
extern "C" void kernel_launch(void* const* d_in, const int* in_sizes, int n_in,
                              void* d_out, int out_size, void* d_ws, size_t ws_size,
                              hipStream_t stream)
{
    const float* x    = (const float*)d_in[0];
    const float* w    = (const float*)d_in[1];
    const float* vals = (const float*)d_in[2];
    const int*   rows = (const int*)d_in[3];
    const int*   cols = (const int*)d_in[4];
    float*       out  = (float*)d_out;
    unsigned short* hb = (unsigned short*)d_ws;   // N_NODES*OUT_DIM bf16 = 12.8 MB

    const int gemm_grid = (N_NODES + 63) / 64;
    gcn_gemm_mfma<<<gemm_grid, 256, 0, stream>>>(x, w, hb);

    const int spmm_grid = (N_NODES + SPMM_ROWS_PER_BLOCK - 1) / SPMM_ROWS_PER_BLOCK;
    gcn_spmm_relu_kernel<<<spmm_grid, 256, 0, stream>>>(hb, vals, rows, cols, out);
}

// Round 6
// 76.337 us; speedup vs baseline: 5.3981x; 1.0280x over previous
//
#include <hip/hip_runtime.h>

#define N_NODES 100000
#define N_EDGES 1600000
#define IN_DIM  256
#define OUT_DIM 64

typedef __attribute__((ext_vector_type(8))) short bf16x8;   // 8 bf16 in 4 VGPRs
typedef __attribute__((ext_vector_type(4))) float f32x4;    // MFMA accumulator

// float -> bf16 (round-to-nearest-even)
__device__ __forceinline__ short f2bf(float f) {
    union { float f; unsigned u; } v; v.f = f;
    unsigned r = v.u + 0x7fffu + ((v.u >> 16) & 1u);
    return (short)(r >> 16);
}

// ---------------------------------------------------------------------------
// GEMM via bf16 MFMA: h = x @ w, stored bf16. (~19 us, near its 16 us HBM
// floor: x read 102.4 MB.) Unchanged.
// ---------------------------------------------------------------------------
#define WB_STRIDE 264   // bf16 elems per n-row: 256 + 8 pad

__global__ __launch_bounds__(256)
void gcn_gemm_mfma(const float* __restrict__ x,
                   const float* __restrict__ w,
                   unsigned short* __restrict__ hb)
{
    __shared__ short wb[OUT_DIM * WB_STRIDE];   // 33792 B

    for (int idx = threadIdx.x; idx < IN_DIM * OUT_DIM; idx += 256) {
        int k = idx >> 6;
        int n = idx & 63;
        wb[n * WB_STRIDE + k] = f2bf(w[idx]);
    }
    __syncthreads();

    const int lane = threadIdx.x & 63;
    const int wv   = threadIdx.x >> 6;
    const int r0   = blockIdx.x * 64 + wv * 16;

    const int arow   = r0 + (lane & 15);
    const int arow_c = arow < N_NODES ? arow : N_NODES - 1;
    const int kbase  = (lane >> 4) << 3;                    // 0,8,16,24
    const float* xr  = x + (size_t)arow_c * IN_DIM + kbase;

    const int nlo = lane & 15;
    const short* wb0 = &wb[(0  + nlo) * WB_STRIDE + kbase];
    const short* wb1 = &wb[(16 + nlo) * WB_STRIDE + kbase];
    const short* wb2 = &wb[(32 + nlo) * WB_STRIDE + kbase];
    const short* wb3 = &wb[(48 + nlo) * WB_STRIDE + kbase];

    f32x4 acc0 = {0.f, 0.f, 0.f, 0.f};
    f32x4 acc1 = {0.f, 0.f, 0.f, 0.f};
    f32x4 acc2 = {0.f, 0.f, 0.f, 0.f};
    f32x4 acc3 = {0.f, 0.f, 0.f, 0.f};

#pragma unroll
    for (int k0 = 0; k0 < IN_DIM; k0 += 32) {
        float4 f0 = *(const float4*)(xr + k0);
        float4 f1 = *(const float4*)(xr + k0 + 4);
        bf16x8 a;
        a[0] = f2bf(f0.x); a[1] = f2bf(f0.y); a[2] = f2bf(f0.z); a[3] = f2bf(f0.w);
        a[4] = f2bf(f1.x); a[5] = f2bf(f1.y); a[6] = f2bf(f1.z); a[7] = f2bf(f1.w);

        bf16x8 b0 = *(const bf16x8*)(wb0 + k0);
        bf16x8 b1 = *(const bf16x8*)(wb1 + k0);
        bf16x8 b2 = *(const bf16x8*)(wb2 + k0);
        bf16x8 b3 = *(const bf16x8*)(wb3 + k0);

        acc0 = __builtin_amdgcn_mfma_f32_16x16x32_bf16(a, b0, acc0, 0, 0, 0);
        acc1 = __builtin_amdgcn_mfma_f32_16x16x32_bf16(a, b1, acc1, 0, 0, 0);
        acc2 = __builtin_amdgcn_mfma_f32_16x16x32_bf16(a, b2, acc2, 0, 0, 0);
        acc3 = __builtin_amdgcn_mfma_f32_16x16x32_bf16(a, b3, acc3, 0, 0, 0);
    }

    const int crow0 = r0 + ((lane >> 4) << 2);
#pragma unroll
    for (int rr = 0; rr < 4; ++rr) {
        int row = crow0 + rr;
        if (row < N_NODES) {
            unsigned short* hp = hb + (size_t)row * OUT_DIM + nlo;
            hp[0]  = (unsigned short)f2bf(acc0[rr]);
            hp[16] = (unsigned short)f2bf(acc1[rr]);
            hp[32] = (unsigned short)f2bf(acc2[rr]);
            hp[48] = (unsigned short)f2bf(acc3[rr]);
        }
    }
}

// ---------------------------------------------------------------------------
// SpMM + ReLU, half-wave-paired gather with an EXPLICIT 8-deep load batch.
// R5 post-mortem: VGPR_Count=32 -> compiler serialized the "independent"
// chains to hit max occupancy. Fix: __launch_bounds__(256,2) frees the
// register budget; the 8-group loop issues all 8 paired gathers (2 KB in
// flight/wave) before any FMA consumes them. Static-index arrays only
// (fully unrolled) so everything stays in registers.
// ---------------------------------------------------------------------------
#define SPMM_ROWS_PER_BLOCK 32
#define SEG_CAP 1024   // mean edges/block = 512, sd ~23; fallback if exceeded

__device__ __forceinline__ int lower_bound_rows(const int* __restrict__ rows, int val)
{
    int lo = 0, hi = N_EDGES;
    while (lo < hi) {
        int mid = (lo + hi) >> 1;
        if (rows[mid] < val) lo = mid + 1; else hi = mid;
    }
    return lo;
}

__global__ __launch_bounds__(256, 2)
void gcn_spmm_relu_kernel(const unsigned short* __restrict__ hb,
                          const float* __restrict__ vals,
                          const int* __restrict__ rows,
                          const int* __restrict__ cols,
                          float* __restrict__ out)
{
    __shared__ int   starts[SPMM_ROWS_PER_BLOCK + 1];
    __shared__ uint2 s_ec[SEG_CAP];   // .x = val bits, .y = col

    const int row0 = blockIdx.x * SPMM_ROWS_PER_BLOCK;
    const int t    = threadIdx.x;

    if (t <= SPMM_ROWS_PER_BLOCK) {
        int target = row0 + t;
        starts[t] = (target >= N_NODES) ? N_EDGES : lower_bound_rows(rows, target);
    }
    __syncthreads();

    const int seg0   = starts[0];
    const int segLen = starts[SPMM_ROWS_PER_BLOCK] - seg0;
    const bool fits  = (segLen <= SEG_CAP);

    if (fits) {
        for (int i = t; i < segLen; i += 256) {
            s_ec[i] = make_uint2(__float_as_uint(vals[seg0 + i]),
                                 (unsigned)cols[seg0 + i]);
        }
    }
    __syncthreads();

    const int lane = t & 63;
    const int wv   = t >> 6;
    const int half = lane >> 5;       // 0: even edges, 1: odd edges
    const int sub  = lane & 31;       // dim pair index: dims 2*sub, 2*sub+1

    for (int rr = wv; rr < SPMM_ROWS_PER_BLOCK; rr += 4) {
        const int r = row0 + rr;                   // N_NODES % 32 == 0, no tail
        const int s = starts[rr]     - seg0;
        const int e = starts[rr + 1] - seg0;
        const int tc = (e - s + 1) >> 1;           // paired iterations

        float aL[4] = {0.f, 0.f, 0.f, 0.f};
        float aH[4] = {0.f, 0.f, 0.f, 0.f};

        if (fits) {
            int i = 0;
            // ---- 8-deep batch: 8 gathers in flight before first consume ----
            for (; i + 8 <= tc; i += 8) {
                float    vv[8];
                unsigned hx[8];
#pragma unroll
                for (int g = 0; g < 8; ++g) {
                    int ei   = s + 2 * (i + g) + half;
                    bool ok  = ei < e;
                    uint2 vc = s_ec[ok ? ei : (e - 1)];
                    vv[g] = ok ? __uint_as_float(vc.x) : 0.f;
                    hx[g] = *(const unsigned*)(hb + (size_t)vc.y * OUT_DIM + 2u * sub);
                }
#pragma unroll
                for (int g = 0; g < 8; ++g) {
                    aL[g & 3] = fmaf(vv[g], __uint_as_float(hx[g] << 16),         aL[g & 3]);
                    aH[g & 3] = fmaf(vv[g], __uint_as_float(hx[g] & 0xffff0000u), aH[g & 3]);
                }
            }
            // ---- 4-deep batch ----
            if (i + 4 <= tc) {
                float    vv[4];
                unsigned hx[4];
#pragma unroll
                for (int g = 0; g < 4; ++g) {
                    int ei   = s + 2 * (i + g) + half;
                    bool ok  = ei < e;
                    uint2 vc = s_ec[ok ? ei : (e - 1)];
                    vv[g] = ok ? __uint_as_float(vc.x) : 0.f;
                    hx[g] = *(const unsigned*)(hb + (size_t)vc.y * OUT_DIM + 2u * sub);
                }
#pragma unroll
                for (int g = 0; g < 4; ++g) {
                    aL[g] = fmaf(vv[g], __uint_as_float(hx[g] << 16),         aL[g]);
                    aH[g] = fmaf(vv[g], __uint_as_float(hx[g] & 0xffff0000u), aH[g]);
                }
                i += 4;
            }
            // ---- scalar tail ----
            for (; i < tc; ++i) {
                int ei   = s + 2 * i + half;
                bool ok  = ei < e;
                uint2 vc = s_ec[ok ? ei : (e - 1)];
                float v  = ok ? __uint_as_float(vc.x) : 0.f;
                unsigned hx = *(const unsigned*)(hb + (size_t)vc.y * OUT_DIM + 2u * sub);
                aL[0] = fmaf(v, __uint_as_float(hx << 16),         aL[0]);
                aH[0] = fmaf(v, __uint_as_float(hx & 0xffff0000u), aH[0]);
            }
        } else {
            // overflow fallback (essentially never): global reads, same pairing
            for (int i = 0; i < tc; ++i) {
                int ei   = s + 2 * i + half;
                bool ok  = ei < e;
                int eidx = (ok ? ei : e - 1) + seg0;
                float v  = ok ? vals[eidx] : 0.f;
                unsigned c = (unsigned)cols[eidx];
                unsigned hx = *(const unsigned*)(hb + (size_t)c * OUT_DIM + 2u * sub);
                aL[0] = fmaf(v, __uint_as_float(hx << 16),         aL[0]);
                aH[0] = fmaf(v, __uint_as_float(hx & 0xffff0000u), aH[0]);
            }
        }

        float lo = (aL[0] + aL[1]) + (aL[2] + aL[3]);
        float hi = (aH[0] + aH[1]) + (aH[2] + aH[3]);
        lo += __shfl_xor(lo, 32);
        hi += __shfl_xor(hi, 32);

        if (half == 0) {
            float2 o;
            o.x = fmaxf(lo, 0.f);
            o.y = fmaxf(hi, 0.f);
            *(float2*)(out + (size_t)r * OUT_DIM + 2u * sub) = o;   // 256B/half-wave
        }
    }
}

// ---------------------------------------------------------------------------
extern "C" void kernel_launch(void* const* d_in, const int* in_sizes, int n_in,
                              void* d_out, int out_size, void* d_ws, size_t ws_size,
                              hipStream_t stream)
{
    const float* x    = (const float*)d_in[0];
    const float* w    = (const float*)d_in[1];
    const float* vals = (const float*)d_in[2];
    const int*   rows = (const int*)d_in[3];
    const int*   cols = (const int*)d_in[4];
    float*       out  = (float*)d_out;
    unsigned short* hb = (unsigned short*)d_ws;   // N_NODES*OUT_DIM bf16 = 12.8 MB

    const int gemm_grid = (N_NODES + 63) / 64;
    gcn_gemm_mfma<<<gemm_grid, 256, 0, stream>>>(x, w, hb);

    const int spmm_grid = (N_NODES + SPMM_ROWS_PER_BLOCK - 1) / SPMM_ROWS_PER_BLOCK;
    gcn_spmm_relu_kernel<<<spmm_grid, 256, 0, stream>>>(hb, vals, rows, cols, out);
}